// Round 5
// baseline (995.615 us; speedup 1.0000x reference)
//
#include <hip/hip_runtime.h>
#include <stdint.h>

// out[M,N] = x[M,K] @ W'[N,K]^T + bias[N], W' = W + SCALE*(loraB @ loraA)
// M = 16384 (B*S), N = 4096, K = 4096. SCALE = 16/16 = 1.0.
#define M_DIM 16384
#define N_DIM 4096
#define K_DIM 4096
#define LORA_SCALE 1.0f

#define BM 256
#define BN 256
#define BK 64
#define NT (K_DIM / BK)  // 64 K-tiles

typedef _Float16 half8 __attribute__((ext_vector_type(8)));
typedef float f32x4 __attribute__((ext_vector_type(4)));

// ---------------------------------------------------------------------------
// Kernel 1 (fused prep), all-streaming:
//  blocks [0, 8192):      W'[n,k] = W[n,k] + sum_r lB[n,r]*lA[r,k] -> f16
//  blocks [8192, 40960):  x fp32 -> f16, 8 elems/thread.
// ---------------------------------------------------------------------------
__global__ __launch_bounds__(256) void prep_kernel(const float* __restrict__ x,
                                                   _Float16* __restrict__ xb,
                                                   const float* __restrict__ W,
                                                   const float* __restrict__ lA,
                                                   const float* __restrict__ lB,
                                                   _Float16* __restrict__ wp) {
    const int t = threadIdx.x;
    const int WBLK = (N_DIM * K_DIM) / (256 * 8);  // 8192

    if (blockIdx.x < WBLK) {
        const size_t base = ((size_t)blockIdx.x * 256 + t) * 8;
        const int n = (int)(base >> 12);           // / K_DIM
        const int k = (int)(base & (K_DIM - 1));
        const int ns = __builtin_amdgcn_readfirstlane(n);
        float Brow[16];
#pragma unroll
        for (int r = 0; r < 16; ++r) Brow[r] = lB[(size_t)ns * 16 + r];

        f32x4 w0 = *(const f32x4*)(W + base);
        f32x4 w1 = *(const f32x4*)(W + base + 4);
        f32x4 d0 = {0.f, 0.f, 0.f, 0.f}, d1 = {0.f, 0.f, 0.f, 0.f};
#pragma unroll
        for (int r = 0; r < 16; ++r) {
            const float* ar = lA + (size_t)r * K_DIM + k;
            f32x4 a0 = *(const f32x4*)ar;
            f32x4 a1 = *(const f32x4*)(ar + 4);
            d0 += Brow[r] * a0;
            d1 += Brow[r] * a1;
        }
        w0 += LORA_SCALE * d0;
        w1 += LORA_SCALE * d1;
        half8 h;
        h[0] = (_Float16)w0[0]; h[1] = (_Float16)w0[1];
        h[2] = (_Float16)w0[2]; h[3] = (_Float16)w0[3];
        h[4] = (_Float16)w1[0]; h[5] = (_Float16)w1[1];
        h[6] = (_Float16)w1[2]; h[7] = (_Float16)w1[3];
        *(half8*)(wp + base) = h;
        return;
    }

    const size_t base = ((size_t)(blockIdx.x - WBLK) * 256 + t) * 8;
    f32x4 a = *(const f32x4*)(x + base);
    f32x4 b = *(const f32x4*)(x + base + 4);
    half8 h;
    h[0] = (_Float16)a[0]; h[1] = (_Float16)a[1];
    h[2] = (_Float16)a[2]; h[3] = (_Float16)a[3];
    h[4] = (_Float16)b[0]; h[5] = (_Float16)b[1];
    h[6] = (_Float16)b[2]; h[7] = (_Float16)b[3];
    *(half8*)(xb + base) = h;
}

// ---------------------------------------------------------------------------
// Kernel 2: 256x256 GEMM, BK=64, 8 waves (2m x 4n). Software-pipelined frag
// reads: each phase issues NEXT phase's ds_reads (double reg buffers ae/ao,
// be/bo), waits counted lgkmcnt(K) (drains only the previous phase's reads),
// then 16 MFMA -> LDS servicing overlaps MFMA. Half-tile ring (8 slots),
// staging 3 half-tiles ahead, counted vmcnt. C=sum_k A[m,k]B[n,k]+bias.
// ---------------------------------------------------------------------------
__device__ __forceinline__ void load_lds16(const void* g, void* l) {
    __builtin_amdgcn_global_load_lds(
        (const __attribute__((address_space(1))) unsigned int*)(uintptr_t)g,
        (__attribute__((address_space(3))) unsigned int*)(uintptr_t)l,
        16, 0, 0);
}

#define BARRIER() do { \
        asm volatile("" ::: "memory"); \
        __builtin_amdgcn_sched_barrier(0); \
        __builtin_amdgcn_s_barrier(); \
        asm volatile("" ::: "memory"); \
    } while (0)
#define WAIT_LGKM(N) do { \
        asm volatile("s_waitcnt lgkmcnt(" #N ")" ::: "memory"); \
        __builtin_amdgcn_sched_barrier(0); \
    } while (0)
#define WAIT_VM(N) do { \
        asm volatile("s_waitcnt vmcnt(" #N ")" ::: "memory"); \
        __builtin_amdgcn_sched_barrier(0); \
    } while (0)

__global__ __launch_bounds__(512, 2) void gemm256_kernel(const _Float16* __restrict__ A,
                                                         const _Float16* __restrict__ B,
                                                         const float* __restrict__ bias,
                                                         float* __restrict__ C) {
    // Slots [dbuf][khalf][256 rows][32 f16]; read swizzle k-slot' = quad ^
    // ((row>>1)&3); staging pre-swizzles the global source col (rule 21).
    __shared__ _Float16 As[2][2][256 * 32];  // 4 x 16 KiB
    __shared__ _Float16 Bs[2][2][256 * 32];  // 4 x 16 KiB -> 128 KiB

    const int tid  = threadIdx.x;
    const int lane = tid & 63;
    const int wave = tid >> 6;
    const int wm   = wave >> 2;   // 0..1 : m-half (128 rows)
    const int wn   = wave & 3;    // 0..3 : n-quarter (64 cols)
    const int quad = lane >> 4;
    const int r16  = lane & 15;
    const int swz  = (quad ^ ((r16 >> 1) & 3)) << 3;

    // XCD-bijective remap: 1024 wgs -> 128 contiguous tiles per XCD.
    const int bid = blockIdx.x;
    const int id  = (bid & 7) * 128 + (bid >> 3);
    const int m0  = (id >> 4) * BM;
    const int n0  = (id & 15) * BN;

    // Staging addressing (per thread, 2 chunks per half-tile).
    const int  srow = tid >> 2;
    const int  scol = (((tid & 3) ^ ((tid >> 3) & 3)) << 3);
    const _Float16* gA = A + (size_t)(m0 + srow) * K_DIM + scol;
    const _Float16* gB = B + (size_t)(n0 + srow) * K_DIM + scol;
    const int ldst0 = tid * 8;
    const int ldst1 = (tid + 512) * 8;

    const int arow = (wm * 128 + r16) * 32 + swz;
    const int brow = (wn * 64 + r16) * 32 + swz;

    f32x4 acc[8][4] = {};
    half8 ae[4], ao[4], be[4], bo[4];

#define ISSUE_A(DB, KH, T) do { \
        const _Float16* g_ = gA + (size_t)((T) * 64 + (KH) * 32); \
        load_lds16(g_, &As[DB][KH][ldst0]); \
        load_lds16(g_ + (size_t)128 * K_DIM, &As[DB][KH][ldst1]); \
    } while (0)
#define ISSUE_B(DB, KH, T) do { \
        const _Float16* g_ = gB + (size_t)((T) * 64 + (KH) * 32); \
        load_lds16(g_, &Bs[DB][KH][ldst0]); \
        load_lds16(g_ + (size_t)128 * K_DIM, &Bs[DB][KH][ldst1]); \
    } while (0)

#define RD_A4(BUF, DB, KH, MH) \
        _Pragma("unroll") \
        for (int i_ = 0; i_ < 4; ++i_) \
            BUF[i_] = *(const half8*)&As[DB][KH][arow + ((MH) * 4 + i_) * 512];
#define RD_B4(BUF, DB, KH) \
        _Pragma("unroll") \
        for (int j_ = 0; j_ < 4; ++j_) \
            BUF[j_] = *(const half8*)&Bs[DB][KH][brow + j_ * 512];

#define MFMA16(BB, AA, MLO) \
        __builtin_amdgcn_s_setprio(1); \
        _Pragma("unroll") \
        for (int i_ = 0; i_ < 4; ++i_) \
            _Pragma("unroll") \
            for (int j_ = 0; j_ < 4; ++j_) \
                acc[(MLO) + i_][j_] = __builtin_amdgcn_mfma_f32_16x16x32_f16( \
                    AA[i_], BB[j_], acc[(MLO) + i_][j_], 0, 0, 0); \
        __builtin_amdgcn_s_setprio(0);

// Phase c0: consumes (be, ae->mh0); pre-reads ao <- As[DB][0] mh1 (for c1).
#define PH0(DB, T1, DOISS) do { \
        RD_A4(ao, DB, 0, 1); \
        if (DOISS) ISSUE_A(1 - (DB), 1, T1); \
        BARRIER(); \
        WAIT_LGKM(4); \
        MFMA16(be, ae, 0) \
        BARRIER(); \
    } while (0)
// Phase c1: consumes (be, ao->mh1); pre-reads bo <- Bs[DB][1], ae <- As[DB][1] mh0.
#define PH1(DB, T2, DOISS) do { \
        RD_B4(bo, DB, 1); \
        RD_A4(ae, DB, 1, 0); \
        if (DOISS) ISSUE_B(DB, 0, T2); \
        BARRIER(); \
        WAIT_LGKM(8); \
        MFMA16(be, ao, 4) \
        BARRIER(); \
    } while (0)
// Phase c2: consumes (bo, ae->mh0); pre-reads ao <- As[DB][1] mh1.
#define PH2(DB, T2, DOISS) do { \
        RD_A4(ao, DB, 1, 1); \
        if (DOISS) ISSUE_A(DB, 0, T2); \
        BARRIER(); \
        WAIT_LGKM(4); \
        MFMA16(bo, ae, 0) \
        BARRIER(); \
    } while (0)
// Phase c3 (steady state): vmcnt(8) ensures next tile's first two slots landed
// chip-wide at the barrier; pre-reads (next c0's be/ae) go AFTER the barrier.
// Ends with counted vmcnt(6) + barrier (tile boundary).
#define PH3(DB, T2) do { \
        WAIT_VM(8); \
        ISSUE_B(DB, 1, T2); \
        BARRIER(); \
        RD_B4(be, 1 - (DB), 0); \
        RD_A4(ae, 1 - (DB), 0, 0); \
        WAIT_LGKM(8); \
        MFMA16(bo, ao, 4) \
        WAIT_VM(6); \
        BARRIER(); \
    } while (0)

    // Prologue: stage t0 fully + 3 half-tiles of t1; land t0; pre-read c0 set.
    ISSUE_B(0, 0, 0); ISSUE_A(0, 0, 0); ISSUE_B(0, 1, 0); ISSUE_A(0, 1, 0);
    ISSUE_B(1, 0, 1); ISSUE_A(1, 0, 1); ISSUE_B(1, 1, 1);
    WAIT_VM(6);
    BARRIER();
    RD_B4(be, 0, 0);
    RD_A4(ae, 0, 0, 0);

#pragma unroll 1
    for (int ip = 0; ip < 31; ++ip) {  // tiles 0..61
        const int t = 2 * ip;
        PH0(0, t + 1, 1); PH1(0, t + 2, 1); PH2(0, t + 2, 1); PH3(0, t + 2);
        PH0(1, t + 2, 1); PH1(1, t + 3, 1); PH2(1, t + 3, 1); PH3(1, t + 3);
    }
    // Tile 62 (DB=0): only stream As[1][1]@63 remains to issue (at PH0).
    PH0(0, 63, 1);
    PH1(0, 0, 0);
    PH2(0, 0, 0);
    // PH3 variant: drain 61's p1/p2 (next c0 slots), pre-read, then full drain.
    WAIT_VM(4);
    BARRIER();
    RD_B4(be, 1, 0);
    RD_A4(ae, 1, 0, 0);
    WAIT_LGKM(8);
    MFMA16(bo, ao, 4)
    WAIT_VM(0);
    BARRIER();
    // Tile 63 (DB=1): no staging left.
    PH0(1, 0, 0);
    PH1(1, 0, 0);
    PH2(1, 0, 0);
    WAIT_LGKM(0);
    MFMA16(bo, ao, 4)

#undef PH0
#undef PH1
#undef PH2
#undef PH3
#undef MFMA16
#undef RD_A4
#undef RD_B4
#undef ISSUE_A
#undef ISSUE_B

    // Epilogue: C/D layout col = lane&15 (n), row = quad*4 + reg (m).
#pragma unroll
    for (int j = 0; j < 4; ++j) {
        const int n = n0 + wn * 64 + j * 16 + r16;
        const float bv = bias[n];
#pragma unroll
        for (int i = 0; i < 8; ++i) {
            const int mbase = m0 + wm * 128 + i * 16 + quad * 4;
#pragma unroll
            for (int r = 0; r < 4; ++r) {
                C[(size_t)(mbase + r) * N_DIM + n] = acc[i][j][r] + bv;
            }
        }
    }
}

// ---------------------------------------------------------------------------
extern "C" void kernel_launch(void* const* d_in, const int* in_sizes, int n_in,
                              void* d_out, int out_size, void* d_ws, size_t ws_size,
                              hipStream_t stream) {
    const float* x      = (const float*)d_in[0];  // [4,4096,4096] fp32 -> [M,K]
    const float* weight = (const float*)d_in[1];  // [N,K] fp32
    const float* bias   = (const float*)d_in[2];  // [N] fp32
    const float* lora_A = (const float*)d_in[3];  // [16,K] fp32
    const float* lora_B = (const float*)d_in[4];  // [N,16] fp32
    float* out = (float*)d_out;

    _Float16* xb = (_Float16*)d_ws;                                       // 128 MiB
    _Float16* wp = (_Float16*)((char*)d_ws + (size_t)M_DIM * K_DIM * 2);  // +32 MiB

    // 1) fused streaming prep: W' (8192 blocks) + x->f16 (32768 blocks)
    const int wblk = (N_DIM * K_DIM) / (256 * 8);
    const int xblk = (int)((M_DIM * (size_t)K_DIM) / (256 * 8));
    prep_kernel<<<dim3(wblk + xblk), dim3(256), 0, stream>>>(x, xb, weight, lora_A, lora_B, wp);
    // 2) GEMM + bias (256x256 tiles, 1024 wgs)
    gemm256_kernel<<<dim3((M_DIM / BM) * (N_DIM / BN)), dim3(512), 0, stream>>>(xb, wp, bias, out);
}